// Round 6
// baseline (618.237 us; speedup 1.0000x reference)
//
#include <hip/hip_runtime.h>
#include <type_traits>

// ---------------------------------------------------------------------------
// RelationalTransformer: B=32 T=4 L=1024 D=1024 H=8 Hd=128 N=15
// out = edge_logits (32*15*15*18 = 129600) ++ energy (32)   [fp32]
//
// Restructure:
//   scores[b,(n,h),l] = qW[b,(n,h),:] . v_f[b,l,:]        (bf16 MFMA, K=e)
//   ctxf[b,(n,h),e]   = attn[b,(n,h),:] . v_fT[b,e,:]     (bf16 MFMA, K=l)
//   bk cancels in softmax; bv applied in ctx GEMM epilogue.
// ---------------------------------------------------------------------------

typedef __attribute__((ext_vector_type(8))) short bf16x8;   // 8 bf16 in 4 VGPRs
typedef __attribute__((ext_vector_type(4))) float f32x4;

__device__ __forceinline__ unsigned short f2bf(float f) {   // RNE float->bf16
    unsigned int u = __float_as_uint(f);
    u = u + 0x7FFFu + ((u >> 16) & 1u);
    return (unsigned short)(u >> 16);
}

// ---------------- generic strided-batched fp32 GEMM:  C = alpha*A@op(B) + bias
// OUTBF: write bf16 (ushort) C instead of fp32.
// v2: reg-prefetch next K-tile before compute (latency hidden under FMAs).
template <int BM, int BN, int BK, int TM, int TN, bool BT, bool OUTBF = false>
__global__ __launch_bounds__(256) void gemm_k(
    const float* __restrict__ A, const float* __restrict__ B,
    const float* __restrict__ bias, void* __restrict__ Cv,
    int M, int N, int K, int lda, int ldb, int ldc,
    long sA1, long sB1, long sC1, long sb1,
    int batch2, long sA2, long sB2, long sC2, long sb2,
    float alpha)
{
    using OutT = typename std::conditional<OUTBF, unsigned short, float>::type;
    const int z  = blockIdx.z;
    const int z1 = z / batch2, z2 = z % batch2;
    A += z1 * sA1 + z2 * sA2;
    B += z1 * sB1 + z2 * sB2;
    OutT* C = ((OutT*)Cv) + z1 * sC1 + z2 * sC2;
    const float* bp = bias ? (bias + z1 * sb1 + z2 * sb2) : nullptr;

    const int m0 = blockIdx.y * BM;
    const int n0 = blockIdx.x * BN;

    __shared__ float As[BK * BM];
    __shared__ float Bs[BK * BN];

    const int t   = threadIdx.x;
    const int TNW = BN / TN;
    const int tn  = t % TNW;
    const int tm  = t / TNW;

    constexpr int ACH = BM * BK / 4;
    constexpr int BCH = BN * BK / 4;
    constexpr int APT = (ACH + 255) / 256;
    constexpr int BPT = (BCH + 255) / 256;

    float acc[TM][TN];
#pragma unroll
    for (int i = 0; i < TM; ++i)
#pragma unroll
        for (int j = 0; j < TN; ++j) acc[i][j] = 0.0f;

    float4 aR[APT], bR[BPT];

    auto loadA = [&](int k0) {
#pragma unroll
        for (int u = 0; u < APT; ++u) {
            const int c = t + u * 256;
            if (ACH % 256 != 0 && c >= ACH) continue;
            const int flat = c * 4;
            const int kq = flat % BK, m = flat / BK;
            float4 v = make_float4(0.f, 0.f, 0.f, 0.f);
            if (m0 + m < M)
                v = *(const float4*)&A[(long)(m0 + m) * lda + k0 + kq];
            aR[u] = v;
        }
    };
    auto writeA = [&]() {
#pragma unroll
        for (int u = 0; u < APT; ++u) {
            const int c = t + u * 256;
            if (ACH % 256 != 0 && c >= ACH) continue;
            const int flat = c * 4;
            const int kq = flat % BK, m = flat / BK;
            As[(kq + 0) * BM + m] = aR[u].x;
            As[(kq + 1) * BM + m] = aR[u].y;
            As[(kq + 2) * BM + m] = aR[u].z;
            As[(kq + 3) * BM + m] = aR[u].w;
        }
    };
    auto loadB = [&](int k0) {
#pragma unroll
        for (int u = 0; u < BPT; ++u) {
            const int c = t + u * 256;
            if (BCH % 256 != 0 && c >= BCH) continue;
            const int flat = c * 4;
            if constexpr (BT) {
                const int kq = flat % BK, n = flat / BK;
                bR[u] = *(const float4*)&B[(long)(n0 + n) * ldb + k0 + kq];
            } else {
                const int n = flat % BN, kq = flat / BN;
                bR[u] = *(const float4*)&B[(long)(k0 + kq) * ldb + n0 + n];
            }
        }
    };
    auto writeB = [&]() {
#pragma unroll
        for (int u = 0; u < BPT; ++u) {
            const int c = t + u * 256;
            if (BCH % 256 != 0 && c >= BCH) continue;
            const int flat = c * 4;
            if constexpr (BT) {
                const int kq = flat % BK, n = flat / BK;
                Bs[(kq + 0) * BN + n] = bR[u].x;
                Bs[(kq + 1) * BN + n] = bR[u].y;
                Bs[(kq + 2) * BN + n] = bR[u].z;
                Bs[(kq + 3) * BN + n] = bR[u].w;
            } else {
                const int n = flat % BN, kq = flat / BN;
                *(float4*)&Bs[kq * BN + n] = bR[u];
            }
        }
    };

    loadA(0); loadB(0);
    for (int k0 = 0; k0 < K; k0 += BK) {
        __syncthreads();                 // prior compute's LDS reads done
        writeA(); writeB();
        const int kn = k0 + BK;
        if (kn < K) { loadA(kn); loadB(kn); }   // prefetch: hides under compute
        __syncthreads();

#pragma unroll
        for (int kk = 0; kk < BK; ++kk) {
            float a[TM], bvv[TN];
            if constexpr (TM == 4) {
                float4 v = *(const float4*)&As[kk * BM + tm * 4];
                a[0] = v.x; a[1] = v.y; a[2] = v.z; a[3] = v.w;
            } else {
#pragma unroll
                for (int i = 0; i < TM; ++i) a[i] = As[kk * BM + tm * TM + i];
            }
            if constexpr (TN == 4) {
                float4 v = *(const float4*)&Bs[kk * BN + tn * 4];
                bvv[0] = v.x; bvv[1] = v.y; bvv[2] = v.z; bvv[3] = v.w;
            } else {
#pragma unroll
                for (int j = 0; j < TN; ++j) bvv[j] = Bs[kk * BN + tn * TN + j];
            }
#pragma unroll
            for (int i = 0; i < TM; ++i)
#pragma unroll
                for (int j = 0; j < TN; ++j) acc[i][j] += a[i] * bvv[j];
        }
    }

#pragma unroll
    for (int i = 0; i < TM; ++i) {
        const int m = m0 + tm * TM + i;
        if (m >= M) continue;
#pragma unroll
        for (int j = 0; j < TN; ++j) {
            const int n = n0 + tn * TN + j;
            float v = acc[i][j] * alpha;
            if (bp) v += bp[n];
            if constexpr (OUTBF)
                C[(long)m * ldc + n] = f2bf(v);
            else
                C[(long)m * ldc + n] = v;
        }
    }
}

// ---------------- bf16 MFMA GEMM v2: C[m][n] = sum_k A[m][k]*B[n][k]
// Tile 64x128, BK=64, 4 waves (2x2). Reg-staged with prefetch; LDS rows are
// 128 B with XOR swizzle (kb ^= (r&7)<<4) at write AND read -> 2 lanes/bank
// on ds_read_b128 (free). Accumulation order identical to v1 (bit-exact).
__global__ __launch_bounds__(256) void bfgemm_k(
    const unsigned short* __restrict__ A, const unsigned short* __restrict__ B,
    float* __restrict__ C, int M, long sA, long sB, long sC)
{
    const int b  = blockIdx.z;
    const int m0 = blockIdx.y * 64;
    const int n0 = blockIdx.x * 128;
    const unsigned short* Ab = A + b * sA;
    const unsigned short* Bb = B + b * sB;
    float* Cb = C + b * sC;

    __shared__ __align__(16) unsigned short As[64 * 64];    // [r][64e swz] 8KB
    __shared__ __align__(16) unsigned short Bs[128 * 64];   // 16KB

    const int t    = threadIdx.x;
    const int lane = t & 63;
    const int w    = t >> 6;
    const int wm   = w >> 1, wn = w & 1;       // wave tile: 32 x 64
    const int lm   = lane & 15, lg = lane >> 4;

    const int sr = t >> 3;              // staging row within 32-row group
    const int sk = (t & 7) * 8;         // staging k offset (elems)

    f32x4 acc[2][4] = {};
    uint4 aR[2], bR[4];

    auto loadT = [&](int k0) {
#pragma unroll
        for (int u = 0; u < 2; ++u)
            aR[u] = *(const uint4*)(Ab + (long)(m0 + u * 32 + sr) * 1024 + k0 + sk);
#pragma unroll
        for (int u = 0; u < 4; ++u)
            bR[u] = *(const uint4*)(Bb + (long)(n0 + u * 32 + sr) * 1024 + k0 + sk);
    };
    auto writeT = [&]() {
#pragma unroll
        for (int u = 0; u < 2; ++u) {
            const int r = u * 32 + sr;
            *(uint4*)&As[r * 64 + (sk ^ ((r & 7) * 8))] = aR[u];
        }
#pragma unroll
        for (int u = 0; u < 4; ++u) {
            const int r = u * 32 + sr;
            *(uint4*)&Bs[r * 64 + (sk ^ ((r & 7) * 8))] = bR[u];
        }
    };

    loadT(0);
    for (int k0 = 0; k0 < 1024; k0 += 64) {
        __syncthreads();                 // prior iter's ds_reads done
        writeT();
        if (k0 + 64 < 1024) loadT(k0 + 64);   // prefetch under compute
        __syncthreads();

#pragma unroll
        for (int ks = 0; ks < 2; ++ks) {
            bf16x8 af[2], bf[4];
#pragma unroll
            for (int fi = 0; fi < 2; ++fi) {
                const int r = wm * 32 + fi * 16 + lm;
                af[fi] = *(const bf16x8*)&As[r * 64 + ((ks * 32 + lg * 8) ^ ((r & 7) * 8))];
            }
#pragma unroll
            for (int fj = 0; fj < 4; ++fj) {
                const int r = wn * 64 + fj * 16 + lm;
                bf[fj] = *(const bf16x8*)&Bs[r * 64 + ((ks * 32 + lg * 8) ^ ((r & 7) * 8))];
            }
#pragma unroll
            for (int fi = 0; fi < 2; ++fi)
#pragma unroll
                for (int fj = 0; fj < 4; ++fj)
                    acc[fi][fj] = __builtin_amdgcn_mfma_f32_16x16x32_bf16(
                        af[fi], bf[fj], acc[fi][fj], 0, 0, 0);
        }
    }

    const int rbase = lg * 4;
    const int cn    = n0 + wn * 64 + lm;
#pragma unroll
    for (int fi = 0; fi < 2; ++fi) {
        const int mb = m0 + wm * 32 + fi * 16 + rbase;
#pragma unroll
        for (int r = 0; r < 4; ++r) {
            const int m = mb + r;
            if (m < M) {
#pragma unroll
                for (int fj = 0; fj < 4; ++fj)
                    Cb[(long)m * 1024 + cn + fj * 16] = acc[fi][fj][r];
            }
        }
    }
}

// ---------------- fused convert: v_bf[b][l][e] and v_bfT[b][e][l] from fp32
// grid (16 e-tiles, 16 l-tiles, 32 b), 64x64 tile. batch stride = T*L*D.
__global__ __launch_bounds__(256) void cvt_k(
    const float* __restrict__ vf, unsigned short* __restrict__ vbf,
    unsigned short* __restrict__ vbfT)
{
    const int b  = blockIdx.z;
    const int e0 = blockIdx.x * 64;
    const int l0 = blockIdx.y * 64;
    const float* src = vf + (long)b * 4194304;   // batch stride = T*L*D
    __shared__ unsigned short tile[64][72];
    const int t = threadIdx.x;
    const int r0 = t >> 4, c0 = (t & 15) * 4;
#pragma unroll
    for (int rr = 0; rr < 4; ++rr) {
        const int r = r0 + rr * 16;
        float4 v = *(const float4*)&src[(long)(l0 + r) * 1024 + e0 + c0];
        ushort4 o;
        o.x = f2bf(v.x); o.y = f2bf(v.y); o.z = f2bf(v.z); o.w = f2bf(v.w);
        tile[r][c0 + 0] = o.x; tile[r][c0 + 1] = o.y;
        tile[r][c0 + 2] = o.z; tile[r][c0 + 3] = o.w;
        *(ushort4*)&vbf[(long)b * 1048576 + (long)(l0 + r) * 1024 + e0 + c0] = o;
    }
    __syncthreads();
#pragma unroll
    for (int rr = 0; rr < 4; ++rr) {
        const int idx = rr * 256 + t;
        const int e   = idx >> 4;
        const int c4  = (idx & 15) * 4;
        ushort4 o;
        o.x = tile[c4 + 0][e]; o.y = tile[c4 + 1][e];
        o.z = tile[c4 + 2][e]; o.w = tile[c4 + 3][e];
        *(ushort4*)&vbfT[(long)b * 1048576 + (long)(e0 + e) * 1024 + l0 + c4] = o;
    }
}

// ---------------- query[b,n,d] = emb[max(node,0)][d] + bboxes . Wb[d,:] + bb[d]
__global__ __launch_bounds__(256) void build_query_k(
    const int* __restrict__ nodes, const float* __restrict__ bboxes,
    const float* __restrict__ emb, const float* __restrict__ Wb,
    const float* __restrict__ bb, float* __restrict__ query)
{
    const int blk = blockIdx.x;
    const int node = nodes[blk];
    const int idx = node < 0 ? 0 : node;
    const float4 bx = *(const float4*)&bboxes[blk * 4];
    const float* er = emb + (long)idx * 1024;
    for (int d = threadIdx.x; d < 1024; d += 256) {
        const float4 w = *(const float4*)&Wb[d * 4];
        query[(long)blk * 1024 + d] =
            er[d] + bb[d] + bx.x * w.x + bx.y * w.y + bx.z * w.z + bx.w * w.w;
    }
}

// ---------------- row softmax over 1024; fp32 in, bf16 out (padded 128 rows/b)
__global__ __launch_bounds__(256) void softmax_k(
    const float* __restrict__ sc, unsigned short* __restrict__ attn)
{
    __shared__ float red[4];
    const int blk = blockIdx.x;              // b*120 + r
    const int b = blk / 120, r = blk % 120;
    const float* p = sc + (long)blk * 1024;
    const int t = threadIdx.x;
    float4 v = *(const float4*)&p[t * 4];

    float m = fmaxf(fmaxf(v.x, v.y), fmaxf(v.z, v.w));
#pragma unroll
    for (int o = 32; o; o >>= 1) m = fmaxf(m, __shfl_xor(m, o));
    if ((t & 63) == 0) red[t >> 6] = m;
    __syncthreads();
    m = fmaxf(fmaxf(red[0], red[1]), fmaxf(red[2], red[3]));
    __syncthreads();

    v.x = __expf(v.x - m); v.y = __expf(v.y - m);
    v.z = __expf(v.z - m); v.w = __expf(v.w - m);
    float s = v.x + v.y + v.z + v.w;
#pragma unroll
    for (int o = 32; o; o >>= 1) s += __shfl_xor(s, o);
    if ((t & 63) == 0) red[t >> 6] = s;
    __syncthreads();
    s = red[0] + red[1] + red[2] + red[3];
    const float inv = 1.0f / s;
    ushort4 o;
    o.x = f2bf(v.x * inv); o.y = f2bf(v.y * inv);
    o.z = f2bf(v.z * inv); o.w = f2bf(v.w * inv);
    *(ushort4*)&attn[(long)(b * 128 + r) * 1024 + t * 4] = o;
}

// ---------------- edge head: one block per (b, i). thread = (j, c).
__global__ __launch_bounds__(320) void edge_k(
    const float* __restrict__ hi, const float* __restrict__ hj,
    const float* __restrict__ W2, const float* __restrict__ b2,
    float* __restrict__ out)
{
    const int b = blockIdx.x, i = blockIdx.y;
    const int t = threadIdx.x;
    __shared__ float hiS[256];
    __shared__ float hjS[15][257];
    __shared__ float w2S[18][257];
    const int j = t / 18, c = t % 18;
    float acc = 0.0f;

    for (int u0 = 0; u0 < 512; u0 += 256) {
        __syncthreads();
        if (t < 64) {
            float4 v = *(const float4*)&hi[(long)(b * 15 + i) * 512 + u0 + t * 4];
            hiS[t * 4 + 0] = v.x; hiS[t * 4 + 1] = v.y;
            hiS[t * 4 + 2] = v.z; hiS[t * 4 + 3] = v.w;
        }
        for (int x = t; x < 960; x += 320) {
            const int r = x >> 6, cc = (x & 63) * 4;
            float4 v = *(const float4*)&hj[(long)(b * 15 + r) * 512 + u0 + cc];
            hjS[r][cc + 0] = v.x; hjS[r][cc + 1] = v.y;
            hjS[r][cc + 2] = v.z; hjS[r][cc + 3] = v.w;
        }
        for (int x = t; x < 1152; x += 320) {
            const int r = x >> 6, cc = (x & 63) * 4;
            float4 v = *(const float4*)&W2[(long)r * 512 + u0 + cc];
            w2S[r][cc + 0] = v.x; w2S[r][cc + 1] = v.y;
            w2S[r][cc + 2] = v.z; w2S[r][cc + 3] = v.w;
        }
        __syncthreads();
        if (t < 270) {
            for (int u = 0; u < 256; ++u) {
                float p = hiS[u] + hjS[j][u];
                p = p > 0.0f ? p : 0.0f;
                acc += p * w2S[c][u];
            }
        }
    }
    if (t < 270)
        out[((long)(b * 15 + i) * 15 + j) * 18 + c] = acc + b2[c];
}

// ---------------- energy stage 1
__global__ __launch_bounds__(256) void energy1_k(
    const float* __restrict__ enr, const int* __restrict__ nodes,
    float* __restrict__ gfeat)
{
    const int b = blockIdx.y;
    const int e = blockIdx.x * 256 + threadIdx.x;
    int cnt = 0;
#pragma unroll
    for (int n = 0; n < 15; ++n) cnt += (nodes[b * 15 + n] != -1) ? 1 : 0;
    const float inv_valid = 1.0f / fmaxf((float)cnt, 1.0f);
    float s = 0.0f;
#pragma unroll
    for (int n = 0; n < 15; ++n) {
        const bool ok = nodes[b * 15 + n] != -1;
        s += ok ? enr[(long)(b * 15 + n) * 1024 + e] : 0.0f;
    }
    gfeat[b * 1024 + e] = s * inv_valid;
}

// ---------------- energy stage 2
__global__ __launch_bounds__(256) void energy2_k(
    const float* __restrict__ gfeat, const float* __restrict__ Wh1,
    const float* __restrict__ bh1, const float* __restrict__ Wh2,
    float* __restrict__ hidr)
{
    const int b  = blockIdx.y;
    const int u0 = blockIdx.x * 16;
    const int t = threadIdx.x;
    __shared__ float gf[1024];
    {
        float4 v = *(const float4*)&gfeat[b * 1024 + t * 4];
        gf[t * 4 + 0] = v.x; gf[t * 4 + 1] = v.y;
        gf[t * 4 + 2] = v.z; gf[t * 4 + 3] = v.w;
    }
    __syncthreads();
    const int wave = t >> 6, lane = t & 63;
#pragma unroll
    for (int r = 0; r < 4; ++r) {
        const int u = u0 + wave * 4 + r;
        float s = 0.0f;
#pragma unroll
        for (int e0 = 0; e0 < 1024; e0 += 64)
            s += gf[e0 + lane] * Wh1[(long)u * 1024 + e0 + lane];
#pragma unroll
        for (int o = 32; o; o >>= 1) s += __shfl_xor(s, o);
        if (lane == 0)
            hidr[b * 256 + u] = fmaxf(s + bh1[u], 0.0f) * Wh2[u];
    }
}

// ---------------- energy stage 3
__global__ __launch_bounds__(256) void energy3_k(
    const float* __restrict__ hidr, const float* __restrict__ bh2,
    float* __restrict__ out)
{
    const int b = blockIdx.x;
    const int t = threadIdx.x;
    __shared__ float red[4];
    float v = hidr[b * 256 + t];
#pragma unroll
    for (int o = 32; o; o >>= 1) v += __shfl_xor(v, o);
    if ((t & 63) == 0) red[t >> 6] = v;
    __syncthreads();
    if (t == 0) out[129600 + b] = red[0] + red[1] + red[2] + red[3] + bh2[0];
}

// ---------------------------------------------------------------------------
extern "C" void kernel_launch(void* const* d_in, const int* in_sizes, int n_in,
                              void* d_out, int out_size, void* d_ws, size_t ws_size,
                              hipStream_t stream)
{
    const float* visual = (const float*)d_in[0];
    const int*   nodes  = (const int*)  d_in[1];
    const float* bboxes = (const float*)d_in[2];
    const float* emb    = (const float*)d_in[3];
    const float* Wb     = (const float*)d_in[4];
    const float* bb     = (const float*)d_in[5];
    const float* Wq     = (const float*)d_in[6];
    const float* bq     = (const float*)d_in[7];
    const float* Wk     = (const float*)d_in[8];
    /* bk (d_in[9]) cancels in softmax */
    const float* Wv     = (const float*)d_in[10];
    const float* bv     = (const float*)d_in[11];
    const float* Wo     = (const float*)d_in[12];
    const float* bo     = (const float*)d_in[13];
    const float* W1     = (const float*)d_in[14];
    const float* b1     = (const float*)d_in[15];
    const float* W2     = (const float*)d_in[16];
    const float* b2     = (const float*)d_in[17];
    const float* Wh1    = (const float*)d_in[18];
    const float* bh1    = (const float*)d_in[19];
    const float* Wh2    = (const float*)d_in[20];
    const float* bh2    = (const float*)d_in[21];

    float* out = (float*)d_out;
    float* ws  = (float*)d_ws;

    // workspace layout (fp32 units)
    float* query  = ws;                       // 480*1024
    float* q      = ws + 491520;              // 480*1024
    float* scores = ws + 983040;              // 32*120*1024 fp32
    float* ctxf   = ws + 4915200;             // 32*120*1024 fp32
    float* ctx    = ws + 8847360;             // 480*1024
    float* enr    = ws + 9338880;             // 480*1024
    float* hi     = ws + 9830400;             // 480*512
    float* hj     = ws + 10076160;            // 480*512
    unsigned short* qW_bf   = (unsigned short*)(ws + 10321920); // 32*128*1024 bf16
    unsigned short* attn_bf = (unsigned short*)(ws + 12419072); // 32*128*1024 bf16
    unsigned short* v_bf    = (unsigned short*)(ws + 14516224); // 32*1024*1024 bf16
    unsigned short* v_bfT   = (unsigned short*)(ws + 31293440); // 32*1024*1024 bf16
    float* gfeat  = query;                    // alias (query dead after q GEMM)
    float* hidr   = query + 32768;            // alias

    const float inv_sqrt_hd = 0.08838834764831845f;  // 1/sqrt(128)
    const float* v_f = visual + 3 * 1048576;         // frame T-1; batch stride 4*1048576

    // 1) query build + v_f bf16 conversion (row + transposed)
    build_query_k<<<480, 256, 0, stream>>>(nodes, bboxes, emb, Wb, bb, query);
    cvt_k<<<dim3(16, 16, 32), 256, 0, stream>>>(v_f, v_bf, v_bfT);

    // 2) q = query @ Wq^T + bq            (480 x 1024, K=1024, fp32)
    gemm_k<64, 64, 32, 4, 4, true><<<dim3(16, 8, 1), 256, 0, stream>>>(
        query, Wq, bq, q, 480, 1024, 1024, 1024, 1024, 1024,
        0, 0, 0, 0, 1, 0, 0, 0, 0, 1.0f);

    // 3) qW_bf[b][(n,h)][e] = (q[b,n,h-slice] @ Wk[h-slice,:]) * inv_sqrt_hd
    //    batched z=(b,h): M=15, N=1024, K=128; bf16 output, padded 128 rows/b
    gemm_k<16, 64, 32, 1, 4, false, true><<<dim3(16, 1, 256), 256, 0, stream>>>(
        q, Wk, nullptr, qW_bf, 15, 1024, 128, 1024, 1024, 8192,
        15360, 0, 131072, 0, 8, 128, 131072, 1024, 0, inv_sqrt_hd);

    // 4) scores[b] = qW_bf[b] @ v_bf[b]^T   (MFMA, M=120 pad 128, N=1024, K=1024)
    bfgemm_k<<<dim3(8, 2, 32), 256, 0, stream>>>(
        qW_bf, v_bf, scores, 120, 131072, 1048576, 122880);

    // 5) softmax over l -> bf16 attn (padded 128 rows/b)
    softmax_k<<<3840, 256, 0, stream>>>(scores, attn_bf);

    // 6) ctxf[b] = attn[b] @ v_bfT[b]^T     (MFMA, K=1024 over tokens)
    bfgemm_k<<<dim3(8, 2, 32), 256, 0, stream>>>(
        attn_bf, v_bfT, ctxf, 120, 131072, 1048576, 122880);

    // 7) ctx[b,:,h] = ctxf[b,(:,h),:] @ Wv_h^T + bv_h   (fp32)
    gemm_k<16, 64, 32, 1, 4, true><<<dim3(2, 1, 256), 256, 0, stream>>>(
        ctxf, Wv, bv, ctx, 15, 128, 1024, 8192, 1024, 1024,
        122880, 0, 15360, 0, 8, 1024, 131072, 128, 128, 1.0f);

    // 8) enriched = ctx @ Wo^T + bo        (480 x 1024, K=1024, fp32)
    gemm_k<64, 64, 32, 4, 4, true><<<dim3(16, 8, 1), 256, 0, stream>>>(
        ctx, Wo, bo, enr, 480, 1024, 1024, 1024, 1024, 1024,
        0, 0, 0, 0, 1, 0, 0, 0, 0, 1.0f);

    // 9) hi = enr @ W1[:, :1024]^T + b1 ;  hj = enr @ W1[:, 1024:]^T  (fp32)
    gemm_k<64, 64, 32, 4, 4, true><<<dim3(8, 8, 1), 256, 0, stream>>>(
        enr, W1, b1, hi, 480, 512, 1024, 1024, 2048, 512,
        0, 0, 0, 0, 1, 0, 0, 0, 0, 1.0f);
    gemm_k<64, 64, 32, 4, 4, true><<<dim3(8, 8, 1), 256, 0, stream>>>(
        enr, W1 + 1024, nullptr, hj, 480, 512, 1024, 1024, 2048, 512,
        0, 0, 0, 0, 1, 0, 0, 0, 0, 1.0f);

    // 10) edge logits -> out[0 .. 129600)
    edge_k<<<dim3(32, 15, 1), 320, 0, stream>>>(hi, hj, W2, b2, out);

    // 11) energy -> out[129600 .. 129632)
    energy1_k<<<dim3(4, 32, 1), 256, 0, stream>>>(enr, nodes, gfeat);
    energy2_k<<<dim3(16, 32, 1), 256, 0, stream>>>(gfeat, Wh1, bh1, Wh2, hidr);
    energy3_k<<<32, 256, 0, stream>>>(hidr, bh2, out);
}

// Round 7
// 605.670 us; speedup vs baseline: 1.0207x; 1.0207x over previous
//
#include <hip/hip_runtime.h>
#include <type_traits>

// ---------------------------------------------------------------------------
// RelationalTransformer: B=32 T=4 L=1024 D=1024 H=8 Hd=128 N=15
// out = edge_logits (32*15*15*18 = 129600) ++ energy (32)   [fp32]
//
// Restructure:
//   scores[b,(n,h),l] = qW[b,(n,h),:] . v_f[b,l,:]        (bf16 MFMA, K=e)
//   ctxf[b,(n,h),e]   = attn[b,(n,h),:] . v_fT[b,e,:]     (bf16 MFMA, K=l)
//   bk cancels in softmax; bv applied in ctx GEMM epilogue.
// ---------------------------------------------------------------------------

typedef __attribute__((ext_vector_type(8))) short bf16x8;   // 8 bf16 in 4 VGPRs
typedef __attribute__((ext_vector_type(4))) float f32x4;

__device__ __forceinline__ unsigned short f2bf(float f) {   // RNE float->bf16
    unsigned int u = __float_as_uint(f);
    u = u + 0x7FFFu + ((u >> 16) & 1u);
    return (unsigned short)(u >> 16);
}

// ---------------- generic strided-batched fp32 GEMM:  C = alpha*A@op(B) + bias
// (exact round-5 v1 body — known-good 512-us baseline contribution)
template <int BM, int BN, int BK, int TM, int TN, bool BT, bool OUTBF = false>
__global__ __launch_bounds__(256) void gemm_k(
    const float* __restrict__ A, const float* __restrict__ B,
    const float* __restrict__ bias, void* __restrict__ Cv,
    int M, int N, int K, int lda, int ldb, int ldc,
    long sA1, long sB1, long sC1, long sb1,
    int batch2, long sA2, long sB2, long sC2, long sb2,
    float alpha)
{
    using OutT = typename std::conditional<OUTBF, unsigned short, float>::type;
    const int z  = blockIdx.z;
    const int z1 = z / batch2, z2 = z % batch2;
    A += z1 * sA1 + z2 * sA2;
    B += z1 * sB1 + z2 * sB2;
    OutT* C = ((OutT*)Cv) + z1 * sC1 + z2 * sC2;
    const float* bp = bias ? (bias + z1 * sb1 + z2 * sb2) : nullptr;

    const int m0 = blockIdx.y * BM;
    const int n0 = blockIdx.x * BN;

    __shared__ float As[BK * BM];
    __shared__ float Bs[BK * BN];

    const int t   = threadIdx.x;
    const int TNW = BN / TN;
    const int tn  = t % TNW;
    const int tm  = t / TNW;

    float acc[TM][TN];
#pragma unroll
    for (int i = 0; i < TM; ++i)
#pragma unroll
        for (int j = 0; j < TN; ++j) acc[i][j] = 0.0f;

    for (int k0 = 0; k0 < K; k0 += BK) {
        constexpr int ACH = BM * BK / 4;
        for (int c = t; c < ACH; c += 256) {
            const int flat = c * 4;
            const int kq = flat % BK, m = flat / BK;
            float4 v = make_float4(0.f, 0.f, 0.f, 0.f);
            if (m0 + m < M)
                v = *(const float4*)&A[(long)(m0 + m) * lda + k0 + kq];
            As[(kq + 0) * BM + m] = v.x;
            As[(kq + 1) * BM + m] = v.y;
            As[(kq + 2) * BM + m] = v.z;
            As[(kq + 3) * BM + m] = v.w;
        }
        constexpr int BCH = BN * BK / 4;
        if constexpr (BT) {
            for (int c = t; c < BCH; c += 256) {
                const int flat = c * 4;
                const int kq = flat % BK, n = flat / BK;
                float4 v = *(const float4*)&B[(long)(n0 + n) * ldb + k0 + kq];
                Bs[(kq + 0) * BN + n] = v.x;
                Bs[(kq + 1) * BN + n] = v.y;
                Bs[(kq + 2) * BN + n] = v.z;
                Bs[(kq + 3) * BN + n] = v.w;
            }
        } else {
            for (int c = t; c < BCH; c += 256) {
                const int flat = c * 4;
                const int n = flat % BN, kq = flat / BN;
                float4 v = *(const float4*)&B[(long)(k0 + kq) * ldb + n0 + n];
                *(float4*)&Bs[kq * BN + n] = v;
            }
        }
        __syncthreads();

#pragma unroll
        for (int kk = 0; kk < BK; ++kk) {
            float a[TM], bvv[TN];
            if constexpr (TM == 4) {
                float4 v = *(const float4*)&As[kk * BM + tm * 4];
                a[0] = v.x; a[1] = v.y; a[2] = v.z; a[3] = v.w;
            } else {
#pragma unroll
                for (int i = 0; i < TM; ++i) a[i] = As[kk * BM + tm * TM + i];
            }
            if constexpr (TN == 4) {
                float4 v = *(const float4*)&Bs[kk * BN + tn * 4];
                bvv[0] = v.x; bvv[1] = v.y; bvv[2] = v.z; bvv[3] = v.w;
            } else {
#pragma unroll
                for (int j = 0; j < TN; ++j) bvv[j] = Bs[kk * BN + tn * TN + j];
            }
#pragma unroll
            for (int i = 0; i < TM; ++i)
#pragma unroll
                for (int j = 0; j < TN; ++j) acc[i][j] += a[i] * bvv[j];
        }
        __syncthreads();
    }

#pragma unroll
    for (int i = 0; i < TM; ++i) {
        const int m = m0 + tm * TM + i;
        if (m >= M) continue;
#pragma unroll
        for (int j = 0; j < TN; ++j) {
            const int n = n0 + tn * TN + j;
            float v = acc[i][j] * alpha;
            if (bp) v += bp[n];
            if constexpr (OUTBF)
                C[(long)m * ldc + n] = f2bf(v);
            else
                C[(long)m * ldc + n] = v;
        }
    }
}

// ---------------- bf16 MFMA GEMM v3: C[m][n] = sum_k A[m][k]*B[n][k]
// Tile 64x128, BK=64, 4 waves (2x2). Same data path & swizzle as v2
// (bit-exact-verified), but RAW-barrier 2-phase schedule: manual
// vmcnt/lgkmcnt + __builtin_amdgcn_s_barrier so next-tile global loads
// stay in flight across the MFMA phase (hipcc drains vmcnt(0) at every
// __syncthreads, which defeated v1/v2's overlap).
__global__ __launch_bounds__(256) void bfgemm_k(
    const unsigned short* __restrict__ A, const unsigned short* __restrict__ B,
    float* __restrict__ C, int M, long sA, long sB, long sC)
{
    const int b  = blockIdx.z;
    const int m0 = blockIdx.y * 64;
    const int n0 = blockIdx.x * 128;
    const unsigned short* Ab = A + b * sA;
    const unsigned short* Bb = B + b * sB;
    float* Cb = C + b * sC;

    __shared__ __align__(16) unsigned short As[64 * 64];    // 8 KB, row-XOR swz
    __shared__ __align__(16) unsigned short Bs[128 * 64];   // 16 KB

    const int t    = threadIdx.x;
    const int lane = t & 63;
    const int w    = t >> 6;
    const int wm   = w >> 1, wn = w & 1;       // wave tile: 32 x 64
    const int lm   = lane & 15, lg = lane >> 4;

    const int sr = t >> 3;              // staging row within 32-row group
    const int sk = (t & 7) * 8;         // staging k offset (elems)

    f32x4 acc[2][4] = {};
    uint4 aR[2], bR[4];

    auto loadT = [&](int k0) {
#pragma unroll
        for (int u = 0; u < 2; ++u)
            aR[u] = *(const uint4*)(Ab + (long)(m0 + u * 32 + sr) * 1024 + k0 + sk);
#pragma unroll
        for (int u = 0; u < 4; ++u)
            bR[u] = *(const uint4*)(Bb + (long)(n0 + u * 32 + sr) * 1024 + k0 + sk);
    };
    auto writeT = [&]() {
#pragma unroll
        for (int u = 0; u < 2; ++u) {
            const int r = u * 32 + sr;
            *(uint4*)&As[r * 64 + (sk ^ ((r & 7) * 8))] = aR[u];
        }
#pragma unroll
        for (int u = 0; u < 4; ++u) {
            const int r = u * 32 + sr;
            *(uint4*)&Bs[r * 64 + (sk ^ ((r & 7) * 8))] = bR[u];
        }
    };

    loadT(0);
    for (int k0 = 0; k0 < 1024; k0 += 64) {
        // wait staged regs (after iter 0 these flew over the prior MFMA phase)
        asm volatile("s_waitcnt vmcnt(0)" ::: "memory");
        __builtin_amdgcn_s_barrier();              // prior iter's ds_reads done
        __builtin_amdgcn_sched_barrier(0);
        writeT();                                   // ds_write staged tile
        if (k0 + 64 < 1024) loadT(k0 + 64);         // issue next tile: in flight
        asm volatile("s_waitcnt lgkmcnt(0)" ::: "memory");  // ds_writes visible
        __builtin_amdgcn_s_barrier();
        __builtin_amdgcn_sched_barrier(0);

#pragma unroll
        for (int ks = 0; ks < 2; ++ks) {
            bf16x8 af[2], bf[4];
#pragma unroll
            for (int fi = 0; fi < 2; ++fi) {
                const int r = wm * 32 + fi * 16 + lm;
                af[fi] = *(const bf16x8*)&As[r * 64 + ((ks * 32 + lg * 8) ^ ((r & 7) * 8))];
            }
#pragma unroll
            for (int fj = 0; fj < 4; ++fj) {
                const int r = wn * 64 + fj * 16 + lm;
                bf[fj] = *(const bf16x8*)&Bs[r * 64 + ((ks * 32 + lg * 8) ^ ((r & 7) * 8))];
            }
#pragma unroll
            for (int fi = 0; fi < 2; ++fi)
#pragma unroll
                for (int fj = 0; fj < 4; ++fj)
                    acc[fi][fj] = __builtin_amdgcn_mfma_f32_16x16x32_bf16(
                        af[fi], bf[fj], acc[fi][fj], 0, 0, 0);
        }
    }

    const int rbase = lg * 4;
    const int cn    = n0 + wn * 64 + lm;
#pragma unroll
    for (int fi = 0; fi < 2; ++fi) {
        const int mb = m0 + wm * 32 + fi * 16 + rbase;
#pragma unroll
        for (int r = 0; r < 4; ++r) {
            const int m = mb + r;
            if (m < M) {
#pragma unroll
                for (int fj = 0; fj < 4; ++fj)
                    Cb[(long)m * 1024 + cn + fj * 16] = acc[fi][fj][r];
            }
        }
    }
}

// ---------------- fused convert: v_bf[b][l][e] and v_bfT[b][e][l] from fp32
__global__ __launch_bounds__(256) void cvt_k(
    const float* __restrict__ vf, unsigned short* __restrict__ vbf,
    unsigned short* __restrict__ vbfT)
{
    const int b  = blockIdx.z;
    const int e0 = blockIdx.x * 64;
    const int l0 = blockIdx.y * 64;
    const float* src = vf + (long)b * 4194304;   // batch stride = T*L*D
    __shared__ unsigned short tile[64][72];
    const int t = threadIdx.x;
    const int r0 = t >> 4, c0 = (t & 15) * 4;
#pragma unroll
    for (int rr = 0; rr < 4; ++rr) {
        const int r = r0 + rr * 16;
        float4 v = *(const float4*)&src[(long)(l0 + r) * 1024 + e0 + c0];
        ushort4 o;
        o.x = f2bf(v.x); o.y = f2bf(v.y); o.z = f2bf(v.z); o.w = f2bf(v.w);
        tile[r][c0 + 0] = o.x; tile[r][c0 + 1] = o.y;
        tile[r][c0 + 2] = o.z; tile[r][c0 + 3] = o.w;
        *(ushort4*)&vbf[(long)b * 1048576 + (long)(l0 + r) * 1024 + e0 + c0] = o;
    }
    __syncthreads();
#pragma unroll
    for (int rr = 0; rr < 4; ++rr) {
        const int idx = rr * 256 + t;
        const int e   = idx >> 4;
        const int c4  = (idx & 15) * 4;
        ushort4 o;
        o.x = tile[c4 + 0][e]; o.y = tile[c4 + 1][e];
        o.z = tile[c4 + 2][e]; o.w = tile[c4 + 3][e];
        *(ushort4*)&vbfT[(long)b * 1048576 + (long)(e0 + e) * 1024 + l0 + c4] = o;
    }
}

// ---------------- query[b,n,d] = emb[max(node,0)][d] + bboxes . Wb[d,:] + bb[d]
__global__ __launch_bounds__(256) void build_query_k(
    const int* __restrict__ nodes, const float* __restrict__ bboxes,
    const float* __restrict__ emb, const float* __restrict__ Wb,
    const float* __restrict__ bb, float* __restrict__ query)
{
    const int blk = blockIdx.x;
    const int node = nodes[blk];
    const int idx = node < 0 ? 0 : node;
    const float4 bx = *(const float4*)&bboxes[blk * 4];
    const float* er = emb + (long)idx * 1024;
    for (int d = threadIdx.x; d < 1024; d += 256) {
        const float4 w = *(const float4*)&Wb[d * 4];
        query[(long)blk * 1024 + d] =
            er[d] + bb[d] + bx.x * w.x + bx.y * w.y + bx.z * w.z + bx.w * w.w;
    }
}

// ---------------- row softmax over 1024; fp32 in, bf16 out (padded 128 rows/b)
__global__ __launch_bounds__(256) void softmax_k(
    const float* __restrict__ sc, unsigned short* __restrict__ attn)
{
    __shared__ float red[4];
    const int blk = blockIdx.x;              // b*120 + r
    const int b = blk / 120, r = blk % 120;
    const float* p = sc + (long)blk * 1024;
    const int t = threadIdx.x;
    float4 v = *(const float4*)&p[t * 4];

    float m = fmaxf(fmaxf(v.x, v.y), fmaxf(v.z, v.w));
#pragma unroll
    for (int o = 32; o; o >>= 1) m = fmaxf(m, __shfl_xor(m, o));
    if ((t & 63) == 0) red[t >> 6] = m;
    __syncthreads();
    m = fmaxf(fmaxf(red[0], red[1]), fmaxf(red[2], red[3]));
    __syncthreads();

    v.x = __expf(v.x - m); v.y = __expf(v.y - m);
    v.z = __expf(v.z - m); v.w = __expf(v.w - m);
    float s = v.x + v.y + v.z + v.w;
#pragma unroll
    for (int o = 32; o; o >>= 1) s += __shfl_xor(s, o);
    if ((t & 63) == 0) red[t >> 6] = s;
    __syncthreads();
    s = red[0] + red[1] + red[2] + red[3];
    const float inv = 1.0f / s;
    ushort4 o;
    o.x = f2bf(v.x * inv); o.y = f2bf(v.y * inv);
    o.z = f2bf(v.z * inv); o.w = f2bf(v.w * inv);
    *(ushort4*)&attn[(long)(b * 128 + r) * 1024 + t * 4] = o;
}

// ---------------- edge head: one block per (b, i). thread = (j, c).
__global__ __launch_bounds__(320) void edge_k(
    const float* __restrict__ hi, const float* __restrict__ hj,
    const float* __restrict__ W2, const float* __restrict__ b2,
    float* __restrict__ out)
{
    const int b = blockIdx.x, i = blockIdx.y;
    const int t = threadIdx.x;
    __shared__ float hiS[256];
    __shared__ float hjS[15][257];
    __shared__ float w2S[18][257];
    const int j = t / 18, c = t % 18;
    float acc = 0.0f;

    for (int u0 = 0; u0 < 512; u0 += 256) {
        __syncthreads();
        if (t < 64) {
            float4 v = *(const float4*)&hi[(long)(b * 15 + i) * 512 + u0 + t * 4];
            hiS[t * 4 + 0] = v.x; hiS[t * 4 + 1] = v.y;
            hiS[t * 4 + 2] = v.z; hiS[t * 4 + 3] = v.w;
        }
        for (int x = t; x < 960; x += 320) {
            const int r = x >> 6, cc = (x & 63) * 4;
            float4 v = *(const float4*)&hj[(long)(b * 15 + r) * 512 + u0 + cc];
            hjS[r][cc + 0] = v.x; hjS[r][cc + 1] = v.y;
            hjS[r][cc + 2] = v.z; hjS[r][cc + 3] = v.w;
        }
        for (int x = t; x < 1152; x += 320) {
            const int r = x >> 6, cc = (x & 63) * 4;
            float4 v = *(const float4*)&W2[(long)r * 512 + u0 + cc];
            w2S[r][cc + 0] = v.x; w2S[r][cc + 1] = v.y;
            w2S[r][cc + 2] = v.z; w2S[r][cc + 3] = v.w;
        }
        __syncthreads();
        if (t < 270) {
            for (int u = 0; u < 256; ++u) {
                float p = hiS[u] + hjS[j][u];
                p = p > 0.0f ? p : 0.0f;
                acc += p * w2S[c][u];
            }
        }
    }
    if (t < 270)
        out[((long)(b * 15 + i) * 15 + j) * 18 + c] = acc + b2[c];
}

// ---------------- energy stage 1
__global__ __launch_bounds__(256) void energy1_k(
    const float* __restrict__ enr, const int* __restrict__ nodes,
    float* __restrict__ gfeat)
{
    const int b = blockIdx.y;
    const int e = blockIdx.x * 256 + threadIdx.x;
    int cnt = 0;
#pragma unroll
    for (int n = 0; n < 15; ++n) cnt += (nodes[b * 15 + n] != -1) ? 1 : 0;
    const float inv_valid = 1.0f / fmaxf((float)cnt, 1.0f);
    float s = 0.0f;
#pragma unroll
    for (int n = 0; n < 15; ++n) {
        const bool ok = nodes[b * 15 + n] != -1;
        s += ok ? enr[(long)(b * 15 + n) * 1024 + e] : 0.0f;
    }
    gfeat[b * 1024 + e] = s * inv_valid;
}

// ---------------- energy stage 2
__global__ __launch_bounds__(256) void energy2_k(
    const float* __restrict__ gfeat, const float* __restrict__ Wh1,
    const float* __restrict__ bh1, const float* __restrict__ Wh2,
    float* __restrict__ hidr)
{
    const int b  = blockIdx.y;
    const int u0 = blockIdx.x * 16;
    const int t = threadIdx.x;
    __shared__ float gf[1024];
    {
        float4 v = *(const float4*)&gfeat[b * 1024 + t * 4];
        gf[t * 4 + 0] = v.x; gf[t * 4 + 1] = v.y;
        gf[t * 4 + 2] = v.z; gf[t * 4 + 3] = v.w;
    }
    __syncthreads();
    const int wave = t >> 6, lane = t & 63;
#pragma unroll
    for (int r = 0; r < 4; ++r) {
        const int u = u0 + wave * 4 + r;
        float s = 0.0f;
#pragma unroll
        for (int e0 = 0; e0 < 1024; e0 += 64)
            s += gf[e0 + lane] * Wh1[(long)u * 1024 + e0 + lane];
#pragma unroll
        for (int o = 32; o; o >>= 1) s += __shfl_xor(s, o);
        if (lane == 0)
            hidr[b * 256 + u] = fmaxf(s + bh1[u], 0.0f) * Wh2[u];
    }
}

// ---------------- energy stage 3
__global__ __launch_bounds__(256) void energy3_k(
    const float* __restrict__ hidr, const float* __restrict__ bh2,
    float* __restrict__ out)
{
    const int b = blockIdx.x;
    const int t = threadIdx.x;
    __shared__ float red[4];
    float v = hidr[b * 256 + t];
#pragma unroll
    for (int o = 32; o; o >>= 1) v += __shfl_xor(v, o);
    if ((t & 63) == 0) red[t >> 6] = v;
    __syncthreads();
    if (t == 0) out[129600 + b] = red[0] + red[1] + red[2] + red[3] + bh2[0];
}

// ---------------------------------------------------------------------------
extern "C" void kernel_launch(void* const* d_in, const int* in_sizes, int n_in,
                              void* d_out, int out_size, void* d_ws, size_t ws_size,
                              hipStream_t stream)
{
    const float* visual = (const float*)d_in[0];
    const int*   nodes  = (const int*)  d_in[1];
    const float* bboxes = (const float*)d_in[2];
    const float* emb    = (const float*)d_in[3];
    const float* Wb     = (const float*)d_in[4];
    const float* bb     = (const float*)d_in[5];
    const float* Wq     = (const float*)d_in[6];
    const float* bq     = (const float*)d_in[7];
    const float* Wk     = (const float*)d_in[8];
    /* bk (d_in[9]) cancels in softmax */
    const float* Wv     = (const float*)d_in[10];
    const float* bv     = (const float*)d_in[11];
    const float* Wo     = (const float*)d_in[12];
    const float* bo     = (const float*)d_in[13];
    const float* W1     = (const float*)d_in[14];
    const float* b1     = (const float*)d_in[15];
    const float* W2     = (const float*)d_in[16];
    const float* b2     = (const float*)d_in[17];
    const float* Wh1    = (const float*)d_in[18];
    const float* bh1    = (const float*)d_in[19];
    const float* Wh2    = (const float*)d_in[20];
    const float* bh2    = (const float*)d_in[21];

    float* out = (float*)d_out;
    float* ws  = (float*)d_ws;

    // workspace layout (fp32 units)
    float* query  = ws;                       // 480*1024
    float* q      = ws + 491520;              // 480*1024
    float* scores = ws + 983040;              // 32*120*1024 fp32
    float* ctxf   = ws + 4915200;             // 32*120*1024 fp32
    float* ctx    = ws + 8847360;             // 480*1024
    float* enr    = ws + 9338880;             // 480*1024
    float* hi     = ws + 9830400;             // 480*512
    float* hj     = ws + 10076160;            // 480*512
    unsigned short* qW_bf   = (unsigned short*)(ws + 10321920); // 32*128*1024 bf16
    unsigned short* attn_bf = (unsigned short*)(ws + 12419072); // 32*128*1024 bf16
    unsigned short* v_bf    = (unsigned short*)(ws + 14516224); // 32*1024*1024 bf16
    unsigned short* v_bfT   = (unsigned short*)(ws + 31293440); // 32*1024*1024 bf16
    float* gfeat  = query;                    // alias (query dead after q GEMM)
    float* hidr   = query + 32768;            // alias

    const float inv_sqrt_hd = 0.08838834764831845f;  // 1/sqrt(128)
    const float* v_f = visual + 3 * 1048576;         // frame T-1; batch stride 4*1048576

    // 1) query build + v_f bf16 conversion (row + transposed)
    build_query_k<<<480, 256, 0, stream>>>(nodes, bboxes, emb, Wb, bb, query);
    cvt_k<<<dim3(16, 16, 32), 256, 0, stream>>>(v_f, v_bf, v_bfT);

    // 2) q = query @ Wq^T + bq            (480 x 1024, K=1024, fp32)
    gemm_k<64, 64, 16, 4, 4, true><<<dim3(16, 8, 1), 256, 0, stream>>>(
        query, Wq, bq, q, 480, 1024, 1024, 1024, 1024, 1024,
        0, 0, 0, 0, 1, 0, 0, 0, 0, 1.0f);

    // 3) qW_bf[b][(n,h)][e] = (q[b,n,h-slice] @ Wk[h-slice,:]) * inv_sqrt_hd
    gemm_k<16, 64, 32, 1, 4, false, true><<<dim3(16, 1, 256), 256, 0, stream>>>(
        q, Wk, nullptr, qW_bf, 15, 1024, 128, 1024, 1024, 8192,
        15360, 0, 131072, 0, 8, 128, 131072, 1024, 0, inv_sqrt_hd);

    // 4) scores[b] = qW_bf[b] @ v_bf[b]^T   (MFMA, M=120 pad 128, N=1024, K=1024)
    bfgemm_k<<<dim3(8, 2, 32), 256, 0, stream>>>(
        qW_bf, v_bf, scores, 120, 131072, 1048576, 122880);

    // 5) softmax over l -> bf16 attn (padded 128 rows/b)
    softmax_k<<<3840, 256, 0, stream>>>(scores, attn_bf);

    // 6) ctxf[b] = attn[b] @ v_bfT[b]^T     (MFMA, K=1024 over tokens)
    bfgemm_k<<<dim3(8, 2, 32), 256, 0, stream>>>(
        attn_bf, v_bfT, ctxf, 120, 131072, 1048576, 122880);

    // 7) ctx[b,:,h] = ctxf[b,(:,h),:] @ Wv_h^T + bv_h   (fp32)
    gemm_k<16, 64, 32, 1, 4, true><<<dim3(2, 1, 256), 256, 0, stream>>>(
        ctxf, Wv, bv, ctx, 15, 128, 1024, 8192, 1024, 1024,
        122880, 0, 15360, 0, 8, 1024, 131072, 128, 128, 1.0f);

    // 8) enriched = ctx @ Wo^T + bo        (480 x 1024, K=1024, fp32)
    gemm_k<64, 64, 16, 4, 4, true><<<dim3(16, 8, 1), 256, 0, stream>>>(
        ctx, Wo, bo, enr, 480, 1024, 1024, 1024, 1024, 1024,
        0, 0, 0, 0, 1, 0, 0, 0, 0, 1.0f);

    // 9) hi = enr @ W1[:, :1024]^T + b1 ;  hj = enr @ W1[:, 1024:]^T  (fp32)
    gemm_k<64, 64, 16, 4, 4, true><<<dim3(8, 8, 1), 256, 0, stream>>>(
        enr, W1, b1, hi, 480, 512, 1024, 1024, 2048, 512,
        0, 0, 0, 0, 1, 0, 0, 0, 0, 1.0f);
    gemm_k<64, 64, 16, 4, 4, true><<<dim3(8, 8, 1), 256, 0, stream>>>(
        enr, W1 + 1024, nullptr, hj, 480, 512, 1024, 1024, 2048, 512,
        0, 0, 0, 0, 1, 0, 0, 0, 0, 1.0f);

    // 10) edge logits -> out[0 .. 129600)
    edge_k<<<dim3(32, 15, 1), 320, 0, stream>>>(hi, hj, W2, b2, out);

    // 11) energy -> out[129600 .. 129632)
    energy1_k<<<dim3(4, 32, 1), 256, 0, stream>>>(enr, nodes, gfeat);
    energy2_k<<<dim3(16, 32, 1), 256, 0, stream>>>(gfeat, Wh1, bh1, Wh2, hidr);
    energy3_k<<<32, 256, 0, stream>>>(hidr, bh2, out);
}

// Round 8
// 550.625 us; speedup vs baseline: 1.1228x; 1.1000x over previous
//
#include <hip/hip_runtime.h>
#include <type_traits>

// ---------------------------------------------------------------------------
// RelationalTransformer: B=32 T=4 L=1024 D=1024 H=8 Hd=128 N=15
// out = edge_logits (32*15*15*18 = 129600) ++ energy (32)   [fp32]
//
// Restructure:
//   scores[b,(n,h),l] = qW[b,(n,h),:] . v_f[b,l,:]        (bf16 MFMA, K=e)
//   ctxf[b,(n,h),e]   = attn[b,(n,h),:] . v_fT[b,e,:]     (bf16 MFMA, K=l)
//   bk cancels in softmax; bv applied in ctx GEMM epilogue.
//
// bfgemm history: v1 LDS+syncthreads 512us total; v2/v3 (BK=64 LDS, raw
// barriers) both ~+100us REGRESSIONS. v4 (this): no LDS, no barriers —
// 1-wave blocks, fragments direct from global (per-batch working set
// = 2.25 MB, fits XCD L2; staging was pure overhead).
// ---------------------------------------------------------------------------

typedef __attribute__((ext_vector_type(8))) short bf16x8;   // 8 bf16 in 4 VGPRs
typedef __attribute__((ext_vector_type(4))) float f32x4;

__device__ __forceinline__ unsigned short f2bf(float f) {   // RNE float->bf16
    unsigned int u = __float_as_uint(f);
    u = u + 0x7FFFu + ((u >> 16) & 1u);
    return (unsigned short)(u >> 16);
}

// ---------------- generic strided-batched fp32 GEMM:  C = alpha*A@op(B) + bias
// (exact round-5 v1 body — known-good 512-us baseline contribution)
template <int BM, int BN, int BK, int TM, int TN, bool BT, bool OUTBF = false>
__global__ __launch_bounds__(256) void gemm_k(
    const float* __restrict__ A, const float* __restrict__ B,
    const float* __restrict__ bias, void* __restrict__ Cv,
    int M, int N, int K, int lda, int ldb, int ldc,
    long sA1, long sB1, long sC1, long sb1,
    int batch2, long sA2, long sB2, long sC2, long sb2,
    float alpha)
{
    using OutT = typename std::conditional<OUTBF, unsigned short, float>::type;
    const int z  = blockIdx.z;
    const int z1 = z / batch2, z2 = z % batch2;
    A += z1 * sA1 + z2 * sA2;
    B += z1 * sB1 + z2 * sB2;
    OutT* C = ((OutT*)Cv) + z1 * sC1 + z2 * sC2;
    const float* bp = bias ? (bias + z1 * sb1 + z2 * sb2) : nullptr;

    const int m0 = blockIdx.y * BM;
    const int n0 = blockIdx.x * BN;

    __shared__ float As[BK * BM];
    __shared__ float Bs[BK * BN];

    const int t   = threadIdx.x;
    const int TNW = BN / TN;
    const int tn  = t % TNW;
    const int tm  = t / TNW;

    float acc[TM][TN];
#pragma unroll
    for (int i = 0; i < TM; ++i)
#pragma unroll
        for (int j = 0; j < TN; ++j) acc[i][j] = 0.0f;

    for (int k0 = 0; k0 < K; k0 += BK) {
        constexpr int ACH = BM * BK / 4;
        for (int c = t; c < ACH; c += 256) {
            const int flat = c * 4;
            const int kq = flat % BK, m = flat / BK;
            float4 v = make_float4(0.f, 0.f, 0.f, 0.f);
            if (m0 + m < M)
                v = *(const float4*)&A[(long)(m0 + m) * lda + k0 + kq];
            As[(kq + 0) * BM + m] = v.x;
            As[(kq + 1) * BM + m] = v.y;
            As[(kq + 2) * BM + m] = v.z;
            As[(kq + 3) * BM + m] = v.w;
        }
        constexpr int BCH = BN * BK / 4;
        if constexpr (BT) {
            for (int c = t; c < BCH; c += 256) {
                const int flat = c * 4;
                const int kq = flat % BK, n = flat / BK;
                float4 v = *(const float4*)&B[(long)(n0 + n) * ldb + k0 + kq];
                Bs[(kq + 0) * BN + n] = v.x;
                Bs[(kq + 1) * BN + n] = v.y;
                Bs[(kq + 2) * BN + n] = v.z;
                Bs[(kq + 3) * BN + n] = v.w;
            }
        } else {
            for (int c = t; c < BCH; c += 256) {
                const int flat = c * 4;
                const int n = flat % BN, kq = flat / BN;
                float4 v = *(const float4*)&B[(long)(k0 + kq) * ldb + n0 + n];
                *(float4*)&Bs[kq * BN + n] = v;
            }
        }
        __syncthreads();

#pragma unroll
        for (int kk = 0; kk < BK; ++kk) {
            float a[TM], bvv[TN];
            if constexpr (TM == 4) {
                float4 v = *(const float4*)&As[kk * BM + tm * 4];
                a[0] = v.x; a[1] = v.y; a[2] = v.z; a[3] = v.w;
            } else {
#pragma unroll
                for (int i = 0; i < TM; ++i) a[i] = As[kk * BM + tm * TM + i];
            }
            if constexpr (TN == 4) {
                float4 v = *(const float4*)&Bs[kk * BN + tn * 4];
                bvv[0] = v.x; bvv[1] = v.y; bvv[2] = v.z; bvv[3] = v.w;
            } else {
#pragma unroll
                for (int j = 0; j < TN; ++j) bvv[j] = Bs[kk * BN + tn * TN + j];
            }
#pragma unroll
            for (int i = 0; i < TM; ++i)
#pragma unroll
                for (int j = 0; j < TN; ++j) acc[i][j] += a[i] * bvv[j];
        }
        __syncthreads();
    }

#pragma unroll
    for (int i = 0; i < TM; ++i) {
        const int m = m0 + tm * TM + i;
        if (m >= M) continue;
#pragma unroll
        for (int j = 0; j < TN; ++j) {
            const int n = n0 + tn * TN + j;
            float v = acc[i][j] * alpha;
            if (bp) v += bp[n];
            if constexpr (OUTBF)
                C[(long)m * ldc + n] = f2bf(v);
            else
                C[(long)m * ldc + n] = v;
        }
    }
}

// ---------------- bf16 MFMA GEMM v4: C[m][n] = sum_k A[m][k]*B[n][k]
// 1-wave workgroup, 32x64 wave tile, NO LDS, NO barriers. Fragments are
// loaded straight from global (L2-resident panels); compiler pipelines
// loads over MFMAs freely. Fragment order (k0 -> fi -> fj) and C store
// mapping identical to v1 -> bit-exact accumulation.
// grid (N/64, Mpad/32, batch), block 64.
__global__ __launch_bounds__(64) void bfgemm_k(
    const unsigned short* __restrict__ A, const unsigned short* __restrict__ B,
    float* __restrict__ C, int M, long sA, long sB, long sC)
{
    const int b  = blockIdx.z;
    const int m0 = blockIdx.y * 32;
    const int n0 = blockIdx.x * 64;

    const int lane = threadIdx.x;
    const int lm = lane & 15, lg = lane >> 4;

    const unsigned short* ap = A + b * sA + (long)(m0 + lm) * 1024 + lg * 8;
    const unsigned short* bp = B + b * sB + (long)(n0 + lm) * 1024 + lg * 8;
    float* Cb = C + b * sC;

    f32x4 acc[2][4] = {};

#pragma unroll 4
    for (int k0 = 0; k0 < 1024; k0 += 32) {
        bf16x8 af[2], bf[4];
#pragma unroll
        for (int fi = 0; fi < 2; ++fi)
            af[fi] = *(const bf16x8*)(ap + fi * 16 * 1024 + k0);
#pragma unroll
        for (int fj = 0; fj < 4; ++fj)
            bf[fj] = *(const bf16x8*)(bp + fj * 16 * 1024 + k0);
#pragma unroll
        for (int fi = 0; fi < 2; ++fi)
#pragma unroll
            for (int fj = 0; fj < 4; ++fj)
                acc[fi][fj] = __builtin_amdgcn_mfma_f32_16x16x32_bf16(
                    af[fi], bf[fj], acc[fi][fj], 0, 0, 0);
    }

    const int rbase = lg * 4;
    const int cn    = n0 + lm;
#pragma unroll
    for (int fi = 0; fi < 2; ++fi) {
        const int mb = m0 + fi * 16 + rbase;
#pragma unroll
        for (int r = 0; r < 4; ++r) {
            const int m = mb + r;
            if (m < M) {
#pragma unroll
                for (int fj = 0; fj < 4; ++fj)
                    Cb[(long)m * 1024 + cn + fj * 16] = acc[fi][fj][r];
            }
        }
    }
}

// ---------------- fused convert: v_bf[b][l][e] and v_bfT[b][e][l] from fp32
__global__ __launch_bounds__(256) void cvt_k(
    const float* __restrict__ vf, unsigned short* __restrict__ vbf,
    unsigned short* __restrict__ vbfT)
{
    const int b  = blockIdx.z;
    const int e0 = blockIdx.x * 64;
    const int l0 = blockIdx.y * 64;
    const float* src = vf + (long)b * 4194304;   // batch stride = T*L*D
    __shared__ unsigned short tile[64][72];
    const int t = threadIdx.x;
    const int r0 = t >> 4, c0 = (t & 15) * 4;
#pragma unroll
    for (int rr = 0; rr < 4; ++rr) {
        const int r = r0 + rr * 16;
        float4 v = *(const float4*)&src[(long)(l0 + r) * 1024 + e0 + c0];
        ushort4 o;
        o.x = f2bf(v.x); o.y = f2bf(v.y); o.z = f2bf(v.z); o.w = f2bf(v.w);
        tile[r][c0 + 0] = o.x; tile[r][c0 + 1] = o.y;
        tile[r][c0 + 2] = o.z; tile[r][c0 + 3] = o.w;
        *(ushort4*)&vbf[(long)b * 1048576 + (long)(l0 + r) * 1024 + e0 + c0] = o;
    }
    __syncthreads();
#pragma unroll
    for (int rr = 0; rr < 4; ++rr) {
        const int idx = rr * 256 + t;
        const int e   = idx >> 4;
        const int c4  = (idx & 15) * 4;
        ushort4 o;
        o.x = tile[c4 + 0][e]; o.y = tile[c4 + 1][e];
        o.z = tile[c4 + 2][e]; o.w = tile[c4 + 3][e];
        *(ushort4*)&vbfT[(long)b * 1048576 + (long)(e0 + e) * 1024 + l0 + c4] = o;
    }
}

// ---------------- query[b,n,d] = emb[max(node,0)][d] + bboxes . Wb[d,:] + bb[d]
__global__ __launch_bounds__(256) void build_query_k(
    const int* __restrict__ nodes, const float* __restrict__ bboxes,
    const float* __restrict__ emb, const float* __restrict__ Wb,
    const float* __restrict__ bb, float* __restrict__ query)
{
    const int blk = blockIdx.x;
    const int node = nodes[blk];
    const int idx = node < 0 ? 0 : node;
    const float4 bx = *(const float4*)&bboxes[blk * 4];
    const float* er = emb + (long)idx * 1024;
    for (int d = threadIdx.x; d < 1024; d += 256) {
        const float4 w = *(const float4*)&Wb[d * 4];
        query[(long)blk * 1024 + d] =
            er[d] + bb[d] + bx.x * w.x + bx.y * w.y + bx.z * w.z + bx.w * w.w;
    }
}

// ---------------- row softmax over 1024; fp32 in, bf16 out (padded 128 rows/b)
__global__ __launch_bounds__(256) void softmax_k(
    const float* __restrict__ sc, unsigned short* __restrict__ attn)
{
    __shared__ float red[4];
    const int blk = blockIdx.x;              // b*120 + r
    const int b = blk / 120, r = blk % 120;
    const float* p = sc + (long)blk * 1024;
    const int t = threadIdx.x;
    float4 v = *(const float4*)&p[t * 4];

    float m = fmaxf(fmaxf(v.x, v.y), fmaxf(v.z, v.w));
#pragma unroll
    for (int o = 32; o; o >>= 1) m = fmaxf(m, __shfl_xor(m, o));
    if ((t & 63) == 0) red[t >> 6] = m;
    __syncthreads();
    m = fmaxf(fmaxf(red[0], red[1]), fmaxf(red[2], red[3]));
    __syncthreads();

    v.x = __expf(v.x - m); v.y = __expf(v.y - m);
    v.z = __expf(v.z - m); v.w = __expf(v.w - m);
    float s = v.x + v.y + v.z + v.w;
#pragma unroll
    for (int o = 32; o; o >>= 1) s += __shfl_xor(s, o);
    if ((t & 63) == 0) red[t >> 6] = s;
    __syncthreads();
    s = red[0] + red[1] + red[2] + red[3];
    const float inv = 1.0f / s;
    ushort4 o;
    o.x = f2bf(v.x * inv); o.y = f2bf(v.y * inv);
    o.z = f2bf(v.z * inv); o.w = f2bf(v.w * inv);
    *(ushort4*)&attn[(long)(b * 128 + r) * 1024 + t * 4] = o;
}

// ---------------- edge head: one block per (b, i). thread = (j, c).
__global__ __launch_bounds__(320) void edge_k(
    const float* __restrict__ hi, const float* __restrict__ hj,
    const float* __restrict__ W2, const float* __restrict__ b2,
    float* __restrict__ out)
{
    const int b = blockIdx.x, i = blockIdx.y;
    const int t = threadIdx.x;
    __shared__ float hiS[256];
    __shared__ float hjS[15][257];
    __shared__ float w2S[18][257];
    const int j = t / 18, c = t % 18;
    float acc = 0.0f;

    for (int u0 = 0; u0 < 512; u0 += 256) {
        __syncthreads();
        if (t < 64) {
            float4 v = *(const float4*)&hi[(long)(b * 15 + i) * 512 + u0 + t * 4];
            hiS[t * 4 + 0] = v.x; hiS[t * 4 + 1] = v.y;
            hiS[t * 4 + 2] = v.z; hiS[t * 4 + 3] = v.w;
        }
        for (int x = t; x < 960; x += 320) {
            const int r = x >> 6, cc = (x & 63) * 4;
            float4 v = *(const float4*)&hj[(long)(b * 15 + r) * 512 + u0 + cc];
            hjS[r][cc + 0] = v.x; hjS[r][cc + 1] = v.y;
            hjS[r][cc + 2] = v.z; hjS[r][cc + 3] = v.w;
        }
        for (int x = t; x < 1152; x += 320) {
            const int r = x >> 6, cc = (x & 63) * 4;
            float4 v = *(const float4*)&W2[(long)r * 512 + u0 + cc];
            w2S[r][cc + 0] = v.x; w2S[r][cc + 1] = v.y;
            w2S[r][cc + 2] = v.z; w2S[r][cc + 3] = v.w;
        }
        __syncthreads();
        if (t < 270) {
            for (int u = 0; u < 256; ++u) {
                float p = hiS[u] + hjS[j][u];
                p = p > 0.0f ? p : 0.0f;
                acc += p * w2S[c][u];
            }
        }
    }
    if (t < 270)
        out[((long)(b * 15 + i) * 15 + j) * 18 + c] = acc + b2[c];
}

// ---------------- energy stage 1
__global__ __launch_bounds__(256) void energy1_k(
    const float* __restrict__ enr, const int* __restrict__ nodes,
    float* __restrict__ gfeat)
{
    const int b = blockIdx.y;
    const int e = blockIdx.x * 256 + threadIdx.x;
    int cnt = 0;
#pragma unroll
    for (int n = 0; n < 15; ++n) cnt += (nodes[b * 15 + n] != -1) ? 1 : 0;
    const float inv_valid = 1.0f / fmaxf((float)cnt, 1.0f);
    float s = 0.0f;
#pragma unroll
    for (int n = 0; n < 15; ++n) {
        const bool ok = nodes[b * 15 + n] != -1;
        s += ok ? enr[(long)(b * 15 + n) * 1024 + e] : 0.0f;
    }
    gfeat[b * 1024 + e] = s * inv_valid;
}

// ---------------- energy stage 2
__global__ __launch_bounds__(256) void energy2_k(
    const float* __restrict__ gfeat, const float* __restrict__ Wh1,
    const float* __restrict__ bh1, const float* __restrict__ Wh2,
    float* __restrict__ hidr)
{
    const int b  = blockIdx.y;
    const int u0 = blockIdx.x * 16;
    const int t = threadIdx.x;
    __shared__ float gf[1024];
    {
        float4 v = *(const float4*)&gfeat[b * 1024 + t * 4];
        gf[t * 4 + 0] = v.x; gf[t * 4 + 1] = v.y;
        gf[t * 4 + 2] = v.z; gf[t * 4 + 3] = v.w;
    }
    __syncthreads();
    const int wave = t >> 6, lane = t & 63;
#pragma unroll
    for (int r = 0; r < 4; ++r) {
        const int u = u0 + wave * 4 + r;
        float s = 0.0f;
#pragma unroll
        for (int e0 = 0; e0 < 1024; e0 += 64)
            s += gf[e0 + lane] * Wh1[(long)u * 1024 + e0 + lane];
#pragma unroll
        for (int o = 32; o; o >>= 1) s += __shfl_xor(s, o);
        if (lane == 0)
            hidr[b * 256 + u] = fmaxf(s + bh1[u], 0.0f) * Wh2[u];
    }
}

// ---------------- energy stage 3
__global__ __launch_bounds__(256) void energy3_k(
    const float* __restrict__ hidr, const float* __restrict__ bh2,
    float* __restrict__ out)
{
    const int b = blockIdx.x;
    const int t = threadIdx.x;
    __shared__ float red[4];
    float v = hidr[b * 256 + t];
#pragma unroll
    for (int o = 32; o; o >>= 1) v += __shfl_xor(v, o);
    if ((t & 63) == 0) red[t >> 6] = v;
    __syncthreads();
    if (t == 0) out[129600 + b] = red[0] + red[1] + red[2] + red[3] + bh2[0];
}

// ---------------------------------------------------------------------------
extern "C" void kernel_launch(void* const* d_in, const int* in_sizes, int n_in,
                              void* d_out, int out_size, void* d_ws, size_t ws_size,
                              hipStream_t stream)
{
    const float* visual = (const float*)d_in[0];
    const int*   nodes  = (const int*)  d_in[1];
    const float* bboxes = (const float*)d_in[2];
    const float* emb    = (const float*)d_in[3];
    const float* Wb     = (const float*)d_in[4];
    const float* bb     = (const float*)d_in[5];
    const float* Wq     = (const float*)d_in[6];
    const float* bq     = (const float*)d_in[7];
    const float* Wk     = (const float*)d_in[8];
    /* bk (d_in[9]) cancels in softmax */
    const float* Wv     = (const float*)d_in[10];
    const float* bv     = (const float*)d_in[11];
    const float* Wo     = (const float*)d_in[12];
    const float* bo     = (const float*)d_in[13];
    const float* W1     = (const float*)d_in[14];
    const float* b1     = (const float*)d_in[15];
    const float* W2     = (const float*)d_in[16];
    const float* b2     = (const float*)d_in[17];
    const float* Wh1    = (const float*)d_in[18];
    const float* bh1    = (const float*)d_in[19];
    const float* Wh2    = (const float*)d_in[20];
    const float* bh2    = (const float*)d_in[21];

    float* out = (float*)d_out;
    float* ws  = (float*)d_ws;

    // workspace layout (fp32 units)
    float* query  = ws;                       // 480*1024
    float* q      = ws + 491520;              // 480*1024
    float* scores = ws + 983040;              // 32*120*1024 fp32
    float* ctxf   = ws + 4915200;             // 32*120*1024 fp32
    float* ctx    = ws + 8847360;             // 480*1024
    float* enr    = ws + 9338880;             // 480*1024
    float* hi     = ws + 9830400;             // 480*512
    float* hj     = ws + 10076160;            // 480*512
    unsigned short* qW_bf   = (unsigned short*)(ws + 10321920); // 32*128*1024 bf16
    unsigned short* attn_bf = (unsigned short*)(ws + 12419072); // 32*128*1024 bf16
    unsigned short* v_bf    = (unsigned short*)(ws + 14516224); // 32*1024*1024 bf16
    unsigned short* v_bfT   = (unsigned short*)(ws + 31293440); // 32*1024*1024 bf16
    float* gfeat  = query;                    // alias (query dead after q GEMM)
    float* hidr   = query + 32768;            // alias

    const float inv_sqrt_hd = 0.08838834764831845f;  // 1/sqrt(128)
    const float* v_f = visual + 3 * 1048576;         // frame T-1; batch stride 4*1048576

    // 1) query build + v_f bf16 conversion (row + transposed)
    build_query_k<<<480, 256, 0, stream>>>(nodes, bboxes, emb, Wb, bb, query);
    cvt_k<<<dim3(16, 16, 32), 256, 0, stream>>>(v_f, v_bf, v_bfT);

    // 2) q = query @ Wq^T + bq            (480 x 1024, K=1024, fp32)
    gemm_k<64, 64, 16, 4, 4, true><<<dim3(16, 8, 1), 256, 0, stream>>>(
        query, Wq, bq, q, 480, 1024, 1024, 1024, 1024, 1024,
        0, 0, 0, 0, 1, 0, 0, 0, 0, 1.0f);

    // 3) qW_bf[b][(n,h)][e] = (q[b,n,h-slice] @ Wk[h-slice,:]) * inv_sqrt_hd
    gemm_k<16, 64, 32, 1, 4, false, true><<<dim3(16, 1, 256), 256, 0, stream>>>(
        q, Wk, nullptr, qW_bf, 15, 1024, 128, 1024, 1024, 8192,
        15360, 0, 131072, 0, 8, 128, 131072, 1024, 0, inv_sqrt_hd);

    // 4) scores[b] = qW_bf[b] @ v_bf[b]^T   (MFMA direct, M=120 pad 128)
    bfgemm_k<<<dim3(16, 4, 32), 64, 0, stream>>>(
        qW_bf, v_bf, scores, 120, 131072, 1048576, 122880);

    // 5) softmax over l -> bf16 attn (padded 128 rows/b)
    softmax_k<<<3840, 256, 0, stream>>>(scores, attn_bf);

    // 6) ctxf[b] = attn[b] @ v_bfT[b]^T     (MFMA direct, K=1024 over tokens)
    bfgemm_k<<<dim3(16, 4, 32), 64, 0, stream>>>(
        attn_bf, v_bfT, ctxf, 120, 131072, 1048576, 122880);

    // 7) ctx[b,:,h] = ctxf[b,(:,h),:] @ Wv_h^T + bv_h   (fp32)
    gemm_k<16, 64, 32, 1, 4, true><<<dim3(2, 1, 256), 256, 0, stream>>>(
        ctxf, Wv, bv, ctx, 15, 128, 1024, 8192, 1024, 1024,
        122880, 0, 15360, 0, 8, 1024, 131072, 128, 128, 1.0f);

    // 8) enriched = ctx @ Wo^T + bo        (480 x 1024, K=1024, fp32)
    gemm_k<64, 64, 16, 4, 4, true><<<dim3(16, 8, 1), 256, 0, stream>>>(
        ctx, Wo, bo, enr, 480, 1024, 1024, 1024, 1024, 1024,
        0, 0, 0, 0, 1, 0, 0, 0, 0, 1.0f);

    // 9) hi = enr @ W1[:, :1024]^T + b1 ;  hj = enr @ W1[:, 1024:]^T  (fp32)
    gemm_k<64, 64, 16, 4, 4, true><<<dim3(8, 8, 1), 256, 0, stream>>>(
        enr, W1, b1, hi, 480, 512, 1024, 1024, 2048, 512,
        0, 0, 0, 0, 1, 0, 0, 0, 0, 1.0f);
    gemm_k<64, 64, 16, 4, 4, true><<<dim3(8, 8, 1), 256, 0, stream>>>(
        enr, W1 + 1024, nullptr, hj, 480, 512, 1024, 1024, 2048, 512,
        0, 0, 0, 0, 1, 0, 0, 0, 0, 1.0f);

    // 10) edge logits -> out[0 .. 129600)
    edge_k<<<dim3(32, 15, 1), 320, 0, stream>>>(hi, hj, W2, b2, out);

    // 11) energy -> out[129600 .. 129632)
    energy1_k<<<dim3(4, 32, 1), 256, 0, stream>>>(enr, nodes, gfeat);
    energy2_k<<<dim3(16, 32, 1), 256, 0, stream>>>(gfeat, Wh1, bh1, Wh2, hidr);
    energy3_k<<<32, 256, 0, stream>>>(hidr, bh2, out);
}